// Round 4
// baseline (81.366 us; speedup 1.0000x reference)
//
#include <hip/hip_runtime.h>
#include <hip/hip_bf16.h>
#include <math.h>

// Hausdorff distance loss, exact EDT.
// pred  [16, 2, 256, 256] f32 logits; target [16, 256, 256] i32 {0,1}.
// pred_lbl = (pred[:,1] > pred[:,0]); dt = exact 2D EDT of each mask.
// out = (sum(pred_lbl * dt(target)) + sum(target * dt(pred_lbl))) / (2*NPIX)
//
// Row pass: one wave per row, shuffle-based cummax scans (no LDS/barriers);
// stashes both binary masks as uchar labels for the col-pass epilogue.
// Col pass: radius-bounded exact min-plus. Candidate y'=y gives upper bound
// U = g2[y,x]; any y' with (y-y')^2 >= U cannot win (g2 >= 0), so scanning
// [y0-r, y0+7+r] with r = floor(sqrt(Umax))+1 is exact for ANY input.
// Loop bounds are wave-uniform (wave-max of r) -> uniform control flow;
// extra candidates are valid y' values, so exactness is preserved.
// Per-block partials (no atomics); finalize tree-reduces 1024 partials.

#define B 16
#define H 256
#define W 256
#define IMG (H * W)            // 65536
#define NPIX (B * IMG)         // 1048576
#define NEGF (-1.0e6f)
#define NINF (-3.0e38f)
#define NBLK 1024              // colpass grid

// ---------------------------------------------------------------------------
// Kernel 1: row pass. One wave (64 lanes) per (m, b, y) row; lane owns x=4l..4l+3.
__global__ __launch_bounds__(256) void rowpass_kernel(
    const float* __restrict__ pred, const int* __restrict__ target,
    float* __restrict__ g2, unsigned char* __restrict__ lbl) {
  const int lane = threadIdx.x & 63;
  const int wid = threadIdx.x >> 6;
  const int row = blockIdx.x * 4 + wid;   // [0, 2*B*H)
  const int m = row >> 12;                // 0: pred mask, 1: target mask
  const int bh = row & 4095;
  const int b = bh >> 8;
  const int y = bh & 255;
  const int x0 = lane * 4;

  bool fg[4];
  if (m == 0) {
    const float* base = pred + (size_t)b * (2 * IMG) + y * W + x0;
    const float4 c0 = *(const float4*)(base);
    const float4 c1 = *(const float4*)(base + IMG);
    fg[0] = c1.x > c0.x; fg[1] = c1.y > c0.y;
    fg[2] = c1.z > c0.z; fg[3] = c1.w > c0.w;
  } else {
    const int4 tv = *(const int4*)(target + (size_t)b * IMG + y * W + x0);
    fg[0] = tv.x == 1; fg[1] = tv.y == 1; fg[2] = tv.z == 1; fg[3] = tv.w == 1;
  }

  uchar4 lb;
  lb.x = fg[0]; lb.y = fg[1]; lb.z = fg[2]; lb.w = fg[3];
  *(uchar4*)(lbl + (size_t)m * NPIX + (size_t)b * IMG + y * W + x0) = lb;

  const float xf0 = (float)x0;

  // ---- left-to-right inclusive cummax of pos_l = fg ? x : NEG
  float p0 = fg[0] ? xf0 : NEGF;
  float p1 = fmaxf(p0, fg[1] ? xf0 + 1.f : NEGF);
  float p2 = fmaxf(p1, fg[2] ? xf0 + 2.f : NEGF);
  float p3 = fmaxf(p2, fg[3] ? xf0 + 3.f : NEGF);
  float s = p3;
#pragma unroll
  for (int off = 1; off < 64; off <<= 1) {
    float u = __shfl_up(s, (unsigned)off);
    if (lane >= off) s = fmaxf(s, u);
  }
  float e = __shfl_up(s, 1u);              // exclusive prefix
  if (lane == 0) e = NINF;
  const float dl0 = xf0 - fmaxf(e, p0);
  const float dl1 = xf0 + 1.f - fmaxf(e, p1);
  const float dl2 = xf0 + 2.f - fmaxf(e, p2);
  const float dl3 = xf0 + 3.f - fmaxf(e, p3);

  // ---- right-to-left inclusive cummax of pos_r = fg ? -x : NEG
  float q3 = fg[3] ? -(xf0 + 3.f) : NEGF;
  float q2 = fmaxf(q3, fg[2] ? -(xf0 + 2.f) : NEGF);
  float q1 = fmaxf(q2, fg[1] ? -(xf0 + 1.f) : NEGF);
  float q0 = fmaxf(q1, fg[0] ? -xf0 : NEGF);
  float t = q0;
#pragma unroll
  for (int off = 1; off < 64; off <<= 1) {
    float u = __shfl_down(t, (unsigned)off);
    if (lane < 64 - off) t = fmaxf(t, u);
  }
  float f = __shfl_down(t, 1u);            // exclusive suffix
  if (lane == 63) f = NINF;
  const float dr0 = -fmaxf(f, q0) - xf0;
  const float dr1 = -fmaxf(f, q1) - (xf0 + 1.f);
  const float dr2 = -fmaxf(f, q2) - (xf0 + 2.f);
  const float dr3 = -fmaxf(f, q3) - (xf0 + 3.f);

  float4 o;
  float v;
  v = fminf(dl0, dr0); o.x = v * v;
  v = fminf(dl1, dr1); o.y = v * v;
  v = fminf(dl2, dr2); o.z = v * v;
  v = fminf(dl3, dr3); o.w = v * v;
  *(float4*)(g2 + (size_t)m * NPIX + (size_t)b * IMG + y * W + x0) = o;
}

// ---------------------------------------------------------------------------
// Kernel 2: radius-bounded column min-plus + fused weighted partial sums.
// Block = 256 thr handles 64 cols x 32 rows; thread owns 8 consecutive y.
// Wave = one ysub group (same y0), so the loop bounds are made wave-uniform.
__global__ __launch_bounds__(256) void colpass_kernel(
    const float* __restrict__ g2, const unsigned char* __restrict__ lbl,
    float* __restrict__ partials) {
  const int tid = threadIdx.x;
  const int bi = blockIdx.x;           // [0, NBLK)
  const int xt = bi & 3;
  const int yt = (bi >> 2) & 7;
  const int m = (bi >> 5) & 1;
  const int b = bi >> 6;
  const int xin = tid & 63;
  const int ysub = tid >> 6;           // 0..3 (== wave id)
  const int x = xt * 64 + xin;
  const int y0 = yt * 32 + ysub * 8;

  const float* __restrict__ gimg = g2 + (size_t)m * NPIX + (size_t)b * IMG;

  float a[8];
#pragma unroll
  for (int k = 0; k < 8; ++k) a[k] = gimg[(y0 + k) * W + x];

  float U = a[0];
#pragma unroll
  for (int k = 1; k < 8; ++k) U = fmaxf(U, a[k]);
  int r = (int)sqrtf(U) + 1;           // exact: (y-y')^2 >= U can't improve
  // wave-uniform radius (lanes share y0); extra candidates stay exact
#pragma unroll
  for (int off = 1; off < 64; off <<= 1) {
    int o = __shfl_xor(r, (unsigned)off);
    r = (o > r) ? o : r;
  }
  int lo = y0 - r; if (lo < 0) lo = 0;
  int hi = y0 + 7 + r; if (hi > H - 1) hi = H - 1;

  for (int yp = lo; yp <= hi; ++yp) {
    const float v = gimg[yp * W + x];
    const float d0 = (float)(y0 - yp);
#pragma unroll
    for (int k = 0; k < 8; ++k) {
      const float d = d0 + (float)k;
      a[k] = fminf(a[k], fmaf(d, d, v));
    }
  }

  // epilogue: dt = sqrt(dt2), weighted by the OTHER mask's labels
  const unsigned char* wl =
      lbl + (size_t)(1 - m) * NPIX + (size_t)b * IMG + y0 * W + x;
  float local = 0.f;
#pragma unroll
  for (int k = 0; k < 8; ++k)
    local += (float)wl[k * W] * sqrtf(a[k]);

  __shared__ float red[256];
  red[tid] = local;
  __syncthreads();
  for (int s = 128; s > 0; s >>= 1) {
    if (tid < s) red[tid] += red[tid + s];
    __syncthreads();
  }
  if (tid == 0) partials[bi] = red[0];
}

// ---------------------------------------------------------------------------
// Kernel 3: reduce NBLK partials -> scalar. One block, deterministic.
__global__ __launch_bounds__(256) void finalize_kernel(
    const float* __restrict__ partials, float* __restrict__ out) {
  const int tid = threadIdx.x;
  float s = 0.f;
#pragma unroll
  for (int i = 0; i < NBLK / 256; ++i) s += partials[i * 256 + tid];
  __shared__ float red[256];
  red[tid] = s;
  __syncthreads();
  for (int k = 128; k > 0; k >>= 1) {
    if (tid < k) red[tid] += red[tid + k];
    __syncthreads();
  }
  if (tid == 0) out[0] = red[0] * (0.5f / (float)NPIX);
}

// ---------------------------------------------------------------------------
extern "C" void kernel_launch(void* const* d_in, const int* in_sizes, int n_in,
                              void* d_out, int out_size, void* d_ws, size_t ws_size,
                              hipStream_t stream) {
  const float* pred = (const float*)d_in[0];     // [16,2,256,256] f32
  const int* target = (const int*)d_in[1];       // [16,256,256] i32
  float* out = (float*)d_out;                    // scalar f32

  float* g2 = (float*)d_ws;                                // 8 MB
  float* partials = g2 + 2 * (size_t)NPIX;                 // NBLK floats
  unsigned char* lbl = (unsigned char*)(partials + NBLK);  // 2 MB

  rowpass_kernel<<<2 * B * H / 4, 256, 0, stream>>>(pred, target, g2, lbl);
  colpass_kernel<<<NBLK, 256, 0, stream>>>(g2, lbl, partials);
  finalize_kernel<<<1, 256, 0, stream>>>(partials, out);
}